// Round 8
// baseline (618.942 us; speedup 1.0000x reference)
//
#include <hip/hip_runtime.h>
#include <hip/hip_bf16.h>
#include <cstdint>

// MFVI second-order CRF, B=32 S=1024 T=256 W=2 ITER=3.
// Round 13: round-12 fused3 + ONE-LINE CORRECTNESS FIX.
//  Bug: per-iteration softmax write-back wrote softmax(0)=uniform 1/256 into
//  out-of-sequence halo rows (s<0 / s>=1024) that must be ZERO (guard-row
//  semantics). Edge tiles then fed spurious uniform P into the output
//  dependency window -> absmax 0.266. Fix: zero the write-back for
//  s outside [0,1024). Rows len<=s<1024 stay uniform (matches reference).
//  Everything else identical to round 12 (redundant-halo fused 3 iters,
//  counted-vmcnt K-loop, 2 blk/CU).
//
// ws: WcTt bf16 [32][1024]x16B @0 (512 KB)

typedef __attribute__((ext_vector_type(4))) float f32x4;
typedef __attribute__((ext_vector_type(8))) short bf16x8;

__device__ __forceinline__ void load_lds16(const void* g, void* l) {
    __builtin_amdgcn_global_load_lds(
        (const __attribute__((address_space(1))) void*)g,
        (__attribute__((address_space(3))) void*)l, 16, 0, 0);
}

// ---------------- prep: tiled+pre-swizzled WcT build ------------------------
// WcTt chunk (p, sl): sl = n*4 + cs holds global k-chunk gk = p*4 +
// (cs ^ ((n>>1)&3)) of logical WcT row n (matches K-loop B-read involution).
__global__ __launch_bounds__(256) void prep_wct(
    const float* __restrict__ trans, __hip_bfloat16* __restrict__ WcTt)
{
    int idx = blockIdx.x * 256 + threadIdx.x;     // 128 blocks -> 32768
    int p = idx >> 10, sl = idx & 1023;
    int n = sl >> 2, cs = sl & 3;
    int gk = p * 4 + (cs ^ ((n >> 1) & 3));
    union { bf16x8 v; __hip_bfloat16 h[8]; } o;
    #pragma unroll
    for (int e = 0; e < 8; ++e) {
        int k = gk * 8 + e;
        int r = k >> 8, kk = k & 255;
        float v;
        if (r == 0)      v = trans[kk * 256 + n];
        else if (r == 1) v = trans[65536 + kk * 256 + n];
        else if (r == 2) v = trans[n * 256 + kk];
        else             v = trans[65536 + n * 256 + kk];
        o.h[e] = __float2bfloat16(v);
    }
    ((bf16x8*)WcTt)[idx] = o.v;
}

// ---------------- fused 3-iteration kernel ----------------------------------
__global__ __launch_bounds__(512, 4) void mfvi_fused3(
    const __hip_bfloat16* __restrict__ WcTt,  // [32][1024] x 16B tiles
    const float* __restrict__ unary, const int* __restrict__ lengths,
    const float* __restrict__ startT, const float* __restrict__ endT,
    float* __restrict__ out)
{
    __shared__ __hip_bfloat16 Ps[84 * 256];       // 43008 B, pr = s - s0 + 10
    __shared__ __hip_bfloat16 Bs[2 * 256 * 32];   // 32768 B
    __shared__ float redA[320];                   // [nslice][lr 0..79]
    __shared__ float redB[320];                   // total 78336 -> 2 blk/CU

    int tid = threadIdx.x;
    int lane = tid & 63, w = tid >> 6;
    int cn = lane & 15, quad = lane >> 4;
    bool wlo = (w < 4);                           // low waves: 3 M-frags
    int wm = wlo ? 0 : 48, wn = (w & 3) * 64;
    int nslice = w & 3;
    int tile = blockIdx.x;                        // 0..511
    int b = tile >> 4, s0 = (tile & 15) << 6;
    int len = lengths[b];

    // ---- prologue: P1 row pr (0..83) = softmax(masked unary row s0+pr-10),
    // zero outside [0,1024). bf16 into swizzled Ps.
    for (int q = 0; q < 11; ++q) {
        int pr = w + q * 8;
        if (pr >= 84) break;
        int s = s0 + pr - 10;
        int ch = lane >> 1;
        int slot = (ch & ~7) | ((ch ^ pr) & 7);
        char* dst = (char*)Ps + pr * 512 + slot * 16 + (lane & 1) * 8;
        if (s >= 0 && s < 1024) {
            float mval = (s < len) ? 1.f : 0.f;
            float4 x = *((const float4*)(unary + ((size_t)((b << 10) + s)) * 256 + lane * 4));
            x.x *= mval; x.y *= mval; x.z *= mval; x.w *= mval;
            float mx = fmaxf(fmaxf(x.x, x.y), fmaxf(x.z, x.w));
            #pragma unroll
            for (int o = 32; o; o >>= 1) mx = fmaxf(mx, __shfl_xor(mx, o));
            float ea = __expf(x.x - mx), eb = __expf(x.y - mx);
            float ec = __expf(x.z - mx), ed = __expf(x.w - mx);
            float sum = ea + eb + ec + ed;
            #pragma unroll
            for (int o = 32; o; o >>= 1) sum += __shfl_xor(sum, o);
            float inv = 1.0f / sum;
            union { ushort4 u; __hip_bfloat16 h[4]; } o4;
            o4.h[0] = __float2bfloat16(ea * inv);
            o4.h[1] = __float2bfloat16(eb * inv);
            o4.h[2] = __float2bfloat16(ec * inv);
            o4.h[3] = __float2bfloat16(ed * inv);
            *((ushort4*)dst) = o4.u;
        } else {
            ushort4 z = {0, 0, 0, 0};
            *((ushort4*)dst) = z;
        }
    }

    // Bs stage for K-step p into buffer bb: linear coalesced 16KB DMA.
    auto stageB = [&](int bb, int p) {
        #pragma unroll
        for (int c = 0; c < 2; ++c) {
            int sl = c * 512 + tid;
            load_lds16((const char*)WcTt + p * 16384 + sl * 16,
                       (char*)Bs + bb * 16384 + sl * 16);
        }
    };

    #pragma unroll 1
    for (int it = 0; it < 3; ++it) {
        __syncthreads();          // Ps ready (prologue or P-write), Bs free
        stageB(0, 0);
        stageB(1, 1);             // 4 loads/thread in flight

        f32x4 acc[3][4] = {};

// ---- counted-vmcnt K-step (round-10 schedule). A-read pr = wm + i*16 +
// cn + 2 + delta (max 83). High waves (wm=48) skip i=2 (wave-uniform).
#define K_STEP(P, VMC, DOSTAGE) do {                                         \
    asm volatile("s_waitcnt vmcnt(" #VMC ")" ::: "memory");                  \
    __builtin_amdgcn_s_barrier();                                            \
    int region = (P) >> 3;                                                   \
    int delta = (region == 0) ? -1 : (region == 1) ? -2                      \
              : (region == 2) ?  1 : 2;                                      \
    int gcb = ((P) & 7) * 4 + quad;                                          \
    bf16x8 af[3], bfv[4];                                                    \
    _Pragma("unroll")                                                        \
    for (int i = 0; i < 2; ++i) {                                            \
        int r = wm + (i << 4) + cn + delta + 2;                              \
        int slot = (gcb & ~7) | ((gcb ^ r) & 7);                             \
        af[i] = *(const bf16x8*)((const char*)Ps + r * 512 + slot * 16);     \
    }                                                                        \
    if (wlo) {                                                               \
        int r = 32 + cn + delta + 2;                                         \
        int slot = (gcb & ~7) | ((gcb ^ r) & 7);                             \
        af[2] = *(const bf16x8*)((const char*)Ps + r * 512 + slot * 16);     \
    }                                                                        \
    _Pragma("unroll")                                                        \
    for (int j = 0; j < 4; ++j) {                                            \
        int n = wn + (j << 4) + cn;                                          \
        int cs = quad ^ ((n >> 1) & 3);                                      \
        bfv[j] = *(const bf16x8*)((const char*)Bs + ((P) & 1) * 16384        \
                                  + n * 64 + cs * 16);                       \
    }                                                                        \
    asm volatile("s_waitcnt lgkmcnt(0)" ::: "memory");                       \
    __builtin_amdgcn_s_barrier();                                            \
    if (DOSTAGE) stageB(((P) & 1), (P) + 2);                                 \
    __builtin_amdgcn_s_setprio(1);                                           \
    _Pragma("unroll")                                                        \
    for (int i = 0; i < 2; ++i)                                              \
        _Pragma("unroll")                                                    \
        for (int j = 0; j < 4; ++j)                                          \
            acc[i][j] = __builtin_amdgcn_mfma_f32_16x16x32_bf16(             \
                af[i], bfv[j], acc[i][j], 0, 0, 0);                          \
    if (wlo) {                                                               \
        _Pragma("unroll")                                                    \
        for (int j = 0; j < 4; ++j)                                          \
            acc[2][j] = __builtin_amdgcn_mfma_f32_16x16x32_bf16(             \
                af[2], bfv[j], acc[2][j], 0, 0, 0);                          \
    }                                                                        \
    __builtin_amdgcn_s_setprio(0);                                           \
} while (0)

        #pragma unroll
        for (int p = 0; p < 30; ++p) K_STEP(p, 2, true);
        K_STEP(30, 2, false);
        K_STEP(31, 0, false);
#undef K_STEP

        // ---- boundary + unary + mask. lr = wm+i*16+quad*4+r, s = s0+lr-8.
        #pragma unroll
        for (int i = 0; i < 3; ++i) {
            if (i == 2 && !wlo) continue;
            #pragma unroll
            for (int j = 0; j < 4; ++j) {
                int n = wn + (j << 4) + cn;
                #pragma unroll
                for (int r = 0; r < 4; ++r) {
                    int lr = wm + (i << 4) + (quad << 2) + r;
                    int s = s0 + lr - 8;
                    float x = acc[i][j][r];
                    if (s == 0)       x += startT[n];
                    if (s == 1)       x += startT[256 + n];
                    if (s == len - 1) x += endT[n];
                    if (s == len - 2) x += endT[256 + n];
                    if (s >= 0 && s < 1024)
                        x += unary[((long)((b << 10) + s)) * 256 + n];
                    acc[i][j][r] = (s >= 0 && s < len) ? x : 0.f;
                }
            }
        }

        if (it == 2) {
            // ---- final: write rows lr in [8,72) -> s in [s0, s0+64)
            #pragma unroll
            for (int i = 0; i < 3; ++i) {
                if (i == 2 && !wlo) continue;
                #pragma unroll
                for (int j = 0; j < 4; ++j) {
                    int n = wn + (j << 4) + cn;
                    #pragma unroll
                    for (int r = 0; r < 4; ++r) {
                        int lr = wm + (i << 4) + (quad << 2) + r;
                        if (lr < 8 || lr >= 72) continue;
                        int s = s0 + lr - 8;
                        out[((long)((b << 10) + s)) * 256 + n] = acc[i][j][r];
                    }
                }
            }
            return;
        }

        // ---- fused row softmax over 256 cols; write P_{it+1} into Ps.
        #pragma unroll
        for (int i = 0; i < 3; ++i) {
            if (i == 2 && !wlo) continue;
            #pragma unroll
            for (int r = 0; r < 4; ++r) {
                float m4 = fmaxf(fmaxf(acc[i][0][r], acc[i][1][r]),
                                 fmaxf(acc[i][2][r], acc[i][3][r]));
                m4 = fmaxf(m4, __shfl_xor(m4, 1));
                m4 = fmaxf(m4, __shfl_xor(m4, 2));
                m4 = fmaxf(m4, __shfl_xor(m4, 4));
                m4 = fmaxf(m4, __shfl_xor(m4, 8));
                if (cn == 0)
                    redA[nslice * 80 + wm + (i << 4) + (quad << 2) + r] = m4;
            }
        }
        __syncthreads();
        float M[3][4];
        #pragma unroll
        for (int i = 0; i < 3; ++i) {
            if (i == 2 && !wlo) continue;
            #pragma unroll
            for (int r = 0; r < 4; ++r) {
                int lr = wm + (i << 4) + (quad << 2) + r;
                M[i][r] = fmaxf(fmaxf(redA[lr], redA[80 + lr]),
                                fmaxf(redA[160 + lr], redA[240 + lr]));
            }
        }
        #pragma unroll
        for (int i = 0; i < 3; ++i) {
            if (i == 2 && !wlo) continue;
            #pragma unroll
            for (int r = 0; r < 4; ++r) {
                float s4 = 0.f;
                #pragma unroll
                for (int j = 0; j < 4; ++j) {
                    float e = __expf(acc[i][j][r] - M[i][r]);
                    acc[i][j][r] = e;
                    s4 += e;
                }
                s4 += __shfl_xor(s4, 1);
                s4 += __shfl_xor(s4, 2);
                s4 += __shfl_xor(s4, 4);
                s4 += __shfl_xor(s4, 8);
                if (cn == 0)
                    redB[nslice * 80 + wm + (i << 4) + (quad << 2) + r] = s4;
            }
        }
        __syncthreads();
        #pragma unroll
        for (int i = 0; i < 3; ++i) {
            if (i == 2 && !wlo) continue;
            #pragma unroll
            for (int r = 0; r < 4; ++r) {
                int lr = wm + (i << 4) + (quad << 2) + r;
                int s = s0 + lr - 8;
                // FIX (round 13): out-of-sequence halo rows must be ZERO
                // (guard-row semantics), not softmax(0)=uniform.
                bool inr = (s >= 0 && s < 1024);
                float inv = 1.0f / (redB[lr] + redB[80 + lr] +
                                    redB[160 + lr] + redB[240 + lr]);
                int pr = lr + 2;
                #pragma unroll
                for (int j = 0; j < 4; ++j) {
                    int n = wn + (j << 4) + cn;
                    int ch = n >> 3;
                    int slot = (ch & ~7) | ((ch ^ pr) & 7);
                    *((__hip_bfloat16*)((char*)Ps + pr * 512 + slot * 16 + (n & 7) * 2)) =
                        __float2bfloat16(inr ? acc[i][j][r] * inv : 0.f);
                }
            }
        }
        // loop-top __syncthreads makes Ps writes visible before next K-loop
    }
}

extern "C" void kernel_launch(void* const* d_in, const int* in_sizes, int n_in,
                              void* d_out, int out_size, void* d_ws, size_t ws_size,
                              hipStream_t stream) {
    const float* unary  = (const float*)d_in[1];
    const float* trans  = (const float*)d_in[3];
    const float* startT = (const float*)d_in[4];
    const float* endT   = (const float*)d_in[5];
    const int*   lens   = (const int*)d_in[6];

    __hip_bfloat16* WcTt = (__hip_bfloat16*)d_ws;    // 512 KB
    float* out = (float*)d_out;

    prep_wct<<<dim3(128), dim3(256), 0, stream>>>(trans, WcTt);
    mfvi_fused3<<<dim3(512), dim3(512), 0, stream>>>(WcTt, unary, lens, startT, endT, out);
}

// Round 10
// 532.180 us; speedup vs baseline: 1.1630x; 1.1630x over previous
//
#include <hip/hip_runtime.h>
#include <hip/hip_bf16.h>
#include <cstdint>

// MFVI second-order CRF, B=32 S=1024 T=256 W=2 ITER=3.
// Round 15 = Round 14 resubmitted (round-9 bench was an infra failure;
// kernel never ran). fused3 SPILL FIX: round-13's `for(it)` loop (unroll 1)
// carried register state across the backedge; under launch_bounds(512,4)'s
// 128-VGPR unified cap this spilled ~313MB/dispatch to scratch (WRITE_SIZE
// 346MB vs 34MB legit; kernel HBM-bound at 1.7TB/s = 465us). Fix:
// instantiate the 3 iterations at COMPILE TIME (macro bodies, per-iteration
// acc scope, no backedge). Only Ps (LDS) carries state between iterations.
// Everything else identical to round 13 (redundant-halo fusion, counted-
// vmcnt K-loop, guard-row-correct writeback, 2 blk/CU).
//
// ws: WcTt bf16 [32][1024]x16B @0 (512 KB)

typedef __attribute__((ext_vector_type(4))) float f32x4;
typedef __attribute__((ext_vector_type(8))) short bf16x8;

__device__ __forceinline__ void load_lds16(const void* g, void* l) {
    __builtin_amdgcn_global_load_lds(
        (const __attribute__((address_space(1))) void*)g,
        (__attribute__((address_space(3))) void*)l, 16, 0, 0);
}

// ---------------- prep: tiled+pre-swizzled WcT build ------------------------
// WcTt chunk (p, sl): sl = n*4 + cs holds global k-chunk gk = p*4 +
// (cs ^ ((n>>1)&3)) of logical WcT row n (matches K-loop B-read involution).
__global__ __launch_bounds__(256) void prep_wct(
    const float* __restrict__ trans, __hip_bfloat16* __restrict__ WcTt)
{
    int idx = blockIdx.x * 256 + threadIdx.x;     // 128 blocks -> 32768
    int p = idx >> 10, sl = idx & 1023;
    int n = sl >> 2, cs = sl & 3;
    int gk = p * 4 + (cs ^ ((n >> 1) & 3));
    union { bf16x8 v; __hip_bfloat16 h[8]; } o;
    #pragma unroll
    for (int e = 0; e < 8; ++e) {
        int k = gk * 8 + e;
        int r = k >> 8, kk = k & 255;
        float v;
        if (r == 0)      v = trans[kk * 256 + n];
        else if (r == 1) v = trans[65536 + kk * 256 + n];
        else if (r == 2) v = trans[n * 256 + kk];
        else             v = trans[65536 + n * 256 + kk];
        o.h[e] = __float2bfloat16(v);
    }
    ((bf16x8*)WcTt)[idx] = o.v;
}

// ---------------- fused 3-iteration kernel ----------------------------------
__global__ __launch_bounds__(512, 4) void mfvi_fused3(
    const __hip_bfloat16* __restrict__ WcTt,  // [32][1024] x 16B tiles
    const float* __restrict__ unary, const int* __restrict__ lengths,
    const float* __restrict__ startT, const float* __restrict__ endT,
    float* __restrict__ out)
{
    __shared__ __hip_bfloat16 Ps[84 * 256];       // 43008 B, pr = s - s0 + 10
    __shared__ __hip_bfloat16 Bs[2 * 256 * 32];   // 32768 B
    __shared__ float redA[320];                   // [nslice][lr 0..79]
    __shared__ float redB[320];                   // total 78336 -> 2 blk/CU

    int tid = threadIdx.x;
    int lane = tid & 63, w = tid >> 6;
    int cn = lane & 15, quad = lane >> 4;
    bool wlo = (w < 4);                           // low waves: 3 M-frags
    int wm = wlo ? 0 : 48, wn = (w & 3) * 64;
    int nslice = w & 3;
    int tile = blockIdx.x;                        // 0..511
    int b = tile >> 4, s0 = (tile & 15) << 6;
    int len = lengths[b];

    // ---- prologue: P1 row pr (0..83) = softmax(masked unary row s0+pr-10),
    // zero outside [0,1024). bf16 into swizzled Ps.
    for (int q = 0; q < 11; ++q) {
        int pr = w + q * 8;
        if (pr >= 84) break;
        int s = s0 + pr - 10;
        int ch = lane >> 1;
        int slot = (ch & ~7) | ((ch ^ pr) & 7);
        char* dst = (char*)Ps + pr * 512 + slot * 16 + (lane & 1) * 8;
        if (s >= 0 && s < 1024) {
            float mval = (s < len) ? 1.f : 0.f;
            float4 x = *((const float4*)(unary + ((size_t)((b << 10) + s)) * 256 + lane * 4));
            x.x *= mval; x.y *= mval; x.z *= mval; x.w *= mval;
            float mx = fmaxf(fmaxf(x.x, x.y), fmaxf(x.z, x.w));
            #pragma unroll
            for (int o = 32; o; o >>= 1) mx = fmaxf(mx, __shfl_xor(mx, o));
            float ea = __expf(x.x - mx), eb = __expf(x.y - mx);
            float ec = __expf(x.z - mx), ed = __expf(x.w - mx);
            float sum = ea + eb + ec + ed;
            #pragma unroll
            for (int o = 32; o; o >>= 1) sum += __shfl_xor(sum, o);
            float inv = 1.0f / sum;
            union { ushort4 u; __hip_bfloat16 h[4]; } o4;
            o4.h[0] = __float2bfloat16(ea * inv);
            o4.h[1] = __float2bfloat16(eb * inv);
            o4.h[2] = __float2bfloat16(ec * inv);
            o4.h[3] = __float2bfloat16(ed * inv);
            *((ushort4*)dst) = o4.u;
        } else {
            ushort4 z = {0, 0, 0, 0};
            *((ushort4*)dst) = z;
        }
    }

    // Bs stage for K-step p into buffer bb: linear coalesced 16KB DMA.
    auto stageB = [&](int bb, int p) {
        #pragma unroll
        for (int c = 0; c < 2; ++c) {
            int sl = c * 512 + tid;
            load_lds16((const char*)WcTt + p * 16384 + sl * 16,
                       (char*)Bs + bb * 16384 + sl * 16);
        }
    };

// ---- counted-vmcnt K-step (round-10 schedule). A-read pr = wm + i*16 +
// cn + 2 + delta (max 83). High waves (wm=48) skip i=2 (wave-uniform).
// References the `acc` in the enclosing iteration scope (textual macro).
#define K_STEP(P, VMC, DOSTAGE) do {                                         \
    asm volatile("s_waitcnt vmcnt(" #VMC ")" ::: "memory");                  \
    __builtin_amdgcn_s_barrier();                                            \
    int region = (P) >> 3;                                                   \
    int delta = (region == 0) ? -1 : (region == 1) ? -2                      \
              : (region == 2) ?  1 : 2;                                      \
    int gcb = ((P) & 7) * 4 + quad;                                          \
    bf16x8 af[3], bfv[4];                                                    \
    _Pragma("unroll")                                                        \
    for (int i = 0; i < 2; ++i) {                                            \
        int r = wm + (i << 4) + cn + delta + 2;                              \
        int slot = (gcb & ~7) | ((gcb ^ r) & 7);                             \
        af[i] = *(const bf16x8*)((const char*)Ps + r * 512 + slot * 16);     \
    }                                                                        \
    if (wlo) {                                                               \
        int r = 32 + cn + delta + 2;                                         \
        int slot = (gcb & ~7) | ((gcb ^ r) & 7);                             \
        af[2] = *(const bf16x8*)((const char*)Ps + r * 512 + slot * 16);     \
    }                                                                        \
    _Pragma("unroll")                                                        \
    for (int j = 0; j < 4; ++j) {                                            \
        int n = wn + (j << 4) + cn;                                          \
        int cs = quad ^ ((n >> 1) & 3);                                      \
        bfv[j] = *(const bf16x8*)((const char*)Bs + ((P) & 1) * 16384        \
                                  + n * 64 + cs * 16);                       \
    }                                                                        \
    asm volatile("s_waitcnt lgkmcnt(0)" ::: "memory");                       \
    __builtin_amdgcn_s_barrier();                                            \
    if (DOSTAGE) stageB(((P) & 1), (P) + 2);                                 \
    __builtin_amdgcn_s_setprio(1);                                           \
    _Pragma("unroll")                                                        \
    for (int i = 0; i < 2; ++i)                                              \
        _Pragma("unroll")                                                    \
        for (int j = 0; j < 4; ++j)                                          \
            acc[i][j] = __builtin_amdgcn_mfma_f32_16x16x32_bf16(             \
                af[i], bfv[j], acc[i][j], 0, 0, 0);                          \
    if (wlo) {                                                               \
        _Pragma("unroll")                                                    \
        for (int j = 0; j < 4; ++j)                                          \
            acc[2][j] = __builtin_amdgcn_mfma_f32_16x16x32_bf16(             \
                af[2], bfv[j], acc[2][j], 0, 0, 0);                          \
    }                                                                        \
    __builtin_amdgcn_s_setprio(0);                                           \
} while (0)

// full K-loop: 32 steps, counted vmcnt, 2-deep prefetch
#define K_LOOP() do {                                                        \
    _Pragma("unroll")                                                        \
    for (int p = 0; p < 30; ++p) K_STEP(p, 2, true);                         \
    K_STEP(30, 2, false);                                                    \
    K_STEP(31, 0, false);                                                    \
} while (0)

// boundary + unary + mask. lr = wm+i*16+quad*4+r, s = s0+lr-8.
#define BOUNDARY_ADD() do {                                                  \
    _Pragma("unroll")                                                        \
    for (int i = 0; i < 3; ++i) {                                            \
        if (i == 2 && !wlo) continue;                                        \
        _Pragma("unroll")                                                    \
        for (int j = 0; j < 4; ++j) {                                        \
            int n = wn + (j << 4) + cn;                                      \
            _Pragma("unroll")                                                \
            for (int r = 0; r < 4; ++r) {                                    \
                int lr = wm + (i << 4) + (quad << 2) + r;                    \
                int s = s0 + lr - 8;                                         \
                float x = acc[i][j][r];                                      \
                if (s == 0)       x += startT[n];                            \
                if (s == 1)       x += startT[256 + n];                      \
                if (s == len - 1) x += endT[n];                              \
                if (s == len - 2) x += endT[256 + n];                        \
                if (s >= 0 && s < 1024)                                      \
                    x += unary[((long)((b << 10) + s)) * 256 + n];           \
                acc[i][j][r] = (s >= 0 && s < len) ? x : 0.f;                \
            }                                                                \
        }                                                                    \
    }                                                                        \
} while (0)

// fused row softmax over 256 cols; write P_{it+1} into Ps (swizzled).
// Out-of-sequence halo rows (s outside [0,1024)) written ZERO (round-13 fix).
#define SOFTMAX_WB() do {                                                    \
    _Pragma("unroll")                                                        \
    for (int i = 0; i < 3; ++i) {                                            \
        if (i == 2 && !wlo) continue;                                        \
        _Pragma("unroll")                                                    \
        for (int r = 0; r < 4; ++r) {                                        \
            float m4 = fmaxf(fmaxf(acc[i][0][r], acc[i][1][r]),              \
                             fmaxf(acc[i][2][r], acc[i][3][r]));             \
            m4 = fmaxf(m4, __shfl_xor(m4, 1));                               \
            m4 = fmaxf(m4, __shfl_xor(m4, 2));                               \
            m4 = fmaxf(m4, __shfl_xor(m4, 4));                               \
            m4 = fmaxf(m4, __shfl_xor(m4, 8));                               \
            if (cn == 0)                                                     \
                redA[nslice * 80 + wm + (i << 4) + (quad << 2) + r] = m4;    \
        }                                                                    \
    }                                                                        \
    __syncthreads();                                                         \
    float M[3][4];                                                           \
    _Pragma("unroll")                                                        \
    for (int i = 0; i < 3; ++i) {                                            \
        if (i == 2 && !wlo) continue;                                        \
        _Pragma("unroll")                                                    \
        for (int r = 0; r < 4; ++r) {                                        \
            int lr = wm + (i << 4) + (quad << 2) + r;                        \
            M[i][r] = fmaxf(fmaxf(redA[lr], redA[80 + lr]),                  \
                            fmaxf(redA[160 + lr], redA[240 + lr]));          \
        }                                                                    \
    }                                                                        \
    _Pragma("unroll")                                                        \
    for (int i = 0; i < 3; ++i) {                                            \
        if (i == 2 && !wlo) continue;                                        \
        _Pragma("unroll")                                                    \
        for (int r = 0; r < 4; ++r) {                                        \
            float s4 = 0.f;                                                  \
            _Pragma("unroll")                                                \
            for (int j = 0; j < 4; ++j) {                                    \
                float e = __expf(acc[i][j][r] - M[i][r]);                    \
                acc[i][j][r] = e;                                            \
                s4 += e;                                                     \
            }                                                                \
            s4 += __shfl_xor(s4, 1);                                         \
            s4 += __shfl_xor(s4, 2);                                         \
            s4 += __shfl_xor(s4, 4);                                         \
            s4 += __shfl_xor(s4, 8);                                         \
            if (cn == 0)                                                     \
                redB[nslice * 80 + wm + (i << 4) + (quad << 2) + r] = s4;    \
        }                                                                    \
    }                                                                        \
    __syncthreads();                                                         \
    _Pragma("unroll")                                                        \
    for (int i = 0; i < 3; ++i) {                                            \
        if (i == 2 && !wlo) continue;                                        \
        _Pragma("unroll")                                                    \
        for (int r = 0; r < 4; ++r) {                                        \
            int lr = wm + (i << 4) + (quad << 2) + r;                        \
            int s = s0 + lr - 8;                                             \
            bool inr = (s >= 0 && s < 1024);                                 \
            float inv = 1.0f / (redB[lr] + redB[80 + lr] +                   \
                                redB[160 + lr] + redB[240 + lr]);            \
            int pr = lr + 2;                                                 \
            _Pragma("unroll")                                                \
            for (int j = 0; j < 4; ++j) {                                    \
                int n = wn + (j << 4) + cn;                                  \
                int ch = n >> 3;                                             \
                int slot = (ch & ~7) | ((ch ^ pr) & 7);                      \
                *((__hip_bfloat16*)((char*)Ps + pr * 512 + slot * 16         \
                                    + (n & 7) * 2)) =                        \
                    __float2bfloat16(inr ? acc[i][j][r] * inv : 0.f);        \
            }                                                                \
        }                                                                    \
    }                                                                        \
} while (0)

    // ================= iteration 0 (compile-time instance) =================
    {
        __syncthreads();              // Ps ready (prologue)
        stageB(0, 0);
        stageB(1, 1);
        f32x4 acc[3][4] = {};
        K_LOOP();
        BOUNDARY_ADD();
        SOFTMAX_WB();
    }   // acc dies here -- no loop-carried register state

    // ================= iteration 1 =========================================
    {
        __syncthreads();              // Ps writeback visible, Bs free
        stageB(0, 0);
        stageB(1, 1);
        f32x4 acc[3][4] = {};
        K_LOOP();
        BOUNDARY_ADD();
        SOFTMAX_WB();
    }

    // ================= iteration 2 (final) =================================
    {
        __syncthreads();
        stageB(0, 0);
        stageB(1, 1);
        f32x4 acc[3][4] = {};
        K_LOOP();
        BOUNDARY_ADD();
        // final: write rows lr in [8,72) -> s in [s0, s0+64)
        #pragma unroll
        for (int i = 0; i < 3; ++i) {
            if (i == 2 && !wlo) continue;
            #pragma unroll
            for (int j = 0; j < 4; ++j) {
                int n = wn + (j << 4) + cn;
                #pragma unroll
                for (int r = 0; r < 4; ++r) {
                    int lr = wm + (i << 4) + (quad << 2) + r;
                    if (lr < 8 || lr >= 72) continue;
                    int s = s0 + lr - 8;
                    out[((long)((b << 10) + s)) * 256 + n] = acc[i][j][r];
                }
            }
        }
    }
#undef K_STEP
#undef K_LOOP
#undef BOUNDARY_ADD
#undef SOFTMAX_WB
}

extern "C" void kernel_launch(void* const* d_in, const int* in_sizes, int n_in,
                              void* d_out, int out_size, void* d_ws, size_t ws_size,
                              hipStream_t stream) {
    const float* unary  = (const float*)d_in[1];
    const float* trans  = (const float*)d_in[3];
    const float* startT = (const float*)d_in[4];
    const float* endT   = (const float*)d_in[5];
    const int*   lens   = (const int*)d_in[6];

    __hip_bfloat16* WcTt = (__hip_bfloat16*)d_ws;    // 512 KB
    float* out = (float*)d_out;

    prep_wct<<<dim3(128), dim3(256), 0, stream>>>(trans, WcTt);
    mfvi_fused3<<<dim3(512), dim3(512), 0, stream>>>(WcTt, unary, lens, startT, endT, out);
}